// Round 11
// baseline (1358.813 us; speedup 1.0000x reference)
//
#include <hip/hip_runtime.h>

// ODENet: y_{t+1} = y_t + f(x_t, y_t),  f = W3^T tanh(W2^T tanh(x*W1[0] + y*W1[1] + b1) + b2) + b3
// out[t][b] = y_t (pre-update state).  SEQ=2048 sequential steps, BATCH=512 independent chains.
//
// Round-11: R10 skeleton, two LDS/drain fixes:
//  - A-fragment reads EXEC-MASKED to the 8 real lanes ((lane&15) in {0,4}); pad lanes hold
//    persistent zeros. A full-wave ds_read_b128 costs ~12 cyc of the CU's single LDS pipe
//    (1 KB/instr); masked it's ~128 B/instr. 32 reads/step/CU: ~384 -> ~50 cyc bank time.
//  - y stored per-step by tid0 IN THE MFMA SHADOW (right after the update), so the store-ack
//    drains during the step instead of stalling wave 0 (and thus all waves) at a barrier.
//  - retained: fold-at-top (-b3/4 partial init, b3 pre-folded into base), exp2-tanh (exact),
//    split DPP reduce, LDA=288 padded A_lds, M=2 chains at MFMA rows 0,4, 1 wave/SIMD.

#define SEQ 2048
#define BATCH 512
#define HID 256
#define LDA 288  // padded row stride (ushorts); rows land on disjoint bank halves

typedef __bf16 bf16x8 __attribute__((ext_vector_type(8)));
typedef short short8 __attribute__((ext_vector_type(8)));
typedef float f32x4 __attribute__((ext_vector_type(4)));

__device__ __forceinline__ unsigned short f2bf_rne(float f) {
  unsigned u = __builtin_bit_cast(unsigned, f);
  u += 0x7fffu + ((u >> 16) & 1u);
  return (unsigned short)(u >> 16);
}

// Exact tanh via exp2: tanh(x) = 1 - 2/(exp2(2*log2e*x) + 1).
// x->+inf: exp2=inf, rcp=0 -> 1.  x->-inf: exp2=0 -> 1-2 = -1.  No clamp needed.
__device__ __forceinline__ float tanh_e(float x) {
  float t = __builtin_amdgcn_exp2f(x * 2.8853900817779268f);
  return __builtin_fmaf(-2.f, __builtin_amdgcn_rcpf(t + 1.f), 1.f);
}

// Sum over each 16-lane DPP row; valid in lane 15 of the row.
__device__ __forceinline__ float row16_sum_to_lane15(float v) {
  int s;
  s = __builtin_amdgcn_update_dpp(0, __builtin_bit_cast(int, v), 0x111, 0xf, 0xf, true);
  v += __builtin_bit_cast(float, s);
  s = __builtin_amdgcn_update_dpp(0, __builtin_bit_cast(int, v), 0x112, 0xf, 0xf, true);
  v += __builtin_bit_cast(float, s);
  s = __builtin_amdgcn_update_dpp(0, __builtin_bit_cast(int, v), 0x114, 0xf, 0xf, true);
  v += __builtin_bit_cast(float, s);
  s = __builtin_amdgcn_update_dpp(0, __builtin_bit_cast(int, v), 0x118, 0xf, 0xf, true);
  v += __builtin_bit_cast(float, s);
  return v;
}

// Pack W2 (256x256 fp32, row-major [k][c]) into bf16 B-fragments.
// ws[(((tile*8)+kc)*64 + lane)*8 + e] = bf16(W2[k][c]) with
//   k = kc*32 + (lane>>4)*8 + e,  c = tile*16 + (lane&15)
__global__ void pack_w2_kernel(const float* __restrict__ W2,
                               unsigned short* __restrict__ ws) {
  int idx = blockIdx.x * 256 + threadIdx.x;     // 0..65535
  int e    = idx & 7;
  int l    = (idx >> 3) & 63;
  int kc   = (idx >> 9) & 7;
  int tile = idx >> 12;                         // 0..15
  int k = kc * 32 + (l >> 4) * 8 + e;
  int c = tile * 16 + (l & 15);
  ws[idx] = f2bf_rne(W2[k * HID + c]);
}

__global__ __launch_bounds__(256, 1) void odenet_kernel(
    const float* __restrict__ x, const float* __restrict__ W1,
    const float* __restrict__ b1, const unsigned short* __restrict__ wsW2,
    const float* __restrict__ b2, const float* __restrict__ W3,
    const float* __restrict__ b3, const float* __restrict__ state0,
    float* __restrict__ out) {
  __shared__ __align__(16) unsigned short A_lds[2 * LDA]; // h1 bf16, padded rows
  __shared__ __align__(16) float partial[2][4];           // [chain][wave]

  const int tid  = threadIdx.x;   // 0..255 == column j
  const int lane = tid & 63;
  const int wave = tid >> 6;      // 0..3
  const int j    = tid;
  const int b0   = blockIdx.x * 2;

  // --- persistent constants ---
  const float w10 = W1[j];
  const float w11 = W1[HID + j];
  const float b1j = b1[j];
  const float b3v = b3[0];
  float b2c[4], w3c[4];
#pragma unroll
  for (int t = 0; t < 4; ++t) {
    const int c = wave * 64 + t * 16 + (lane & 15);
    b2c[t] = b2[c];
    w3c[t] = W3[c];
  }

  // --- B fragments: wave owns tiles wave*4 .. wave*4+3 (64 columns) ---
  short8 bf[4][8];
  {
    const short8* wp = (const short8*)wsW2;
#pragma unroll
    for (int t = 0; t < 4; ++t)
#pragma unroll
      for (int kc = 0; kc < 8; ++kc)
        bf[t][kc] = wp[((wave * 4 + t) * 8 + kc) * 64 + lane];
  }

  // --- A fragments: only rows m=0 (chain0, lane&15==0) and m=4 (chain1, lane&15==4)
  //     carry real data; pad lanes hold PERSISTENT zeros (never overwritten).
  //     Masked reads: 8 active lanes x 16 B = 128 B of LDS bank traffic per instr.
  const short8 zero8 = {0, 0, 0, 0, 0, 0, 0, 0};
  short8 areg[8];
#pragma unroll
  for (int kc = 0; kc < 8; ++kc) areg[kc] = zero8;
  const bool aread = ((lane & 11) == 0);              // lane&15 in {0,4}
  const int  aoff  = ((lane >> 2) & 1) * LDA + (lane >> 4) * 8; // ushort index

  const f32x4 kZero = {0.f, 0.f, 0.f, 0.f};

  float y0 = state0[b0];
  float y1 = state0[b0 + 1];

  const float* xp = x + b0;
  float* yo = out + b0;

  // x prefetch double buffer (8 steps ahead); xa_r = x_r*W1[0,j] + b1[j]
  float2 xb[8], xn[8];
  float xa0[8], xa1[8];
#pragma unroll
  for (int i = 0; i < 8; ++i) xb[i] = *(const float2*)&xp[i * BATCH];
#pragma unroll
  for (int i = 0; i < 8; ++i) {
    xa0[i] = xb[i].x * w10 + b1j;
    xa1[i] = xb[i].y * w10 + b1j;
  }

  // --- prologue: partials init so step-0 fold yields sum = -b3 -> pre = base, f = 0 ---
  if (tid < 8) ((float*)partial)[tid] = -0.25f * b3v;
  // base'' = xa + w11*y + w11*b3 (b3 pre-folded; fold's sum carries -b3 at step 0)
  float base0 = __builtin_fmaf(b3v, w11, __builtin_fmaf(y0, w11, xa0[0]));
  float base1 = __builtin_fmaf(b3v, w11, __builtin_fmaf(y1, w11, xa1[0]));
  __syncthreads(); // partials visible (acts as the "bar2" preceding step 0)

  for (int tb = 0; tb < SEQ; tb += 8) {
    if (tb + 8 < SEQ) {
      const float* xq = xp + (tb + 8) * BATCH;
#pragma unroll
      for (int i = 0; i < 8; ++i) xn[i] = *(const float2*)&xq[i * BATCH];
    }

#pragma unroll
    for (int i = 0; i < 8; ++i) {
      const int t = tb + i;

      // --- fold partials of step t-1 (post-bar2 critical path): 3 adds + fma + tanh ---
      const f32x4 q0 = *(const f32x4*)&partial[0][0];
      const f32x4 q1 = *(const f32x4*)&partial[1][0];
      const float s0sum = (q0[0] + q0[1]) + (q0[2] + q0[3]); // = f(t-1) - b3
      const float s1sum = (q1[0] + q1[1]) + (q1[2] + q1[3]);
      const float pre0 = __builtin_fmaf(s0sum, w11, base0);  // b3 already inside base
      const float pre1 = __builtin_fmaf(s1sum, w11, base1);
      A_lds[j]       = f2bf_rne(tanh_e(pre0));
      A_lds[LDA + j] = f2bf_rne(tanh_e(pre1));
      __syncthreads(); // bar1: h1 visible

      // --- A-fragments: MASKED reads (8 real lanes; pad lanes keep persistent zeros) ---
      if (aread) {
#pragma unroll
        for (int kc = 0; kc < 8; ++kc)
          areg[kc] = *(const short8*)&A_lds[aoff + kc * 32];
      }

      // --- tiles 0,1: K=256 over 8 chunks (2 indep acc chains) ---
      f32x4 acc0, acc1, acc2, acc3;
      {
        const bf16x8 a = __builtin_bit_cast(bf16x8, areg[0]);
        acc0 = __builtin_amdgcn_mfma_f32_16x16x32_bf16(a, __builtin_bit_cast(bf16x8, bf[0][0]), kZero, 0, 0, 0);
        acc1 = __builtin_amdgcn_mfma_f32_16x16x32_bf16(a, __builtin_bit_cast(bf16x8, bf[1][0]), kZero, 0, 0, 0);
      }
#pragma unroll
      for (int kc = 1; kc < 8; ++kc) {
        const bf16x8 a = __builtin_bit_cast(bf16x8, areg[kc]);
        acc0 = __builtin_amdgcn_mfma_f32_16x16x32_bf16(a, __builtin_bit_cast(bf16x8, bf[0][kc]), acc0, 0, 0, 0);
        acc1 = __builtin_amdgcn_mfma_f32_16x16x32_bf16(a, __builtin_bit_cast(bf16x8, bf[1][kc]), acc1, 0, 0, 0);
      }

      // --- off-path work in the MFMA shadow: y update (-> Y_t), STORE, next base ---
      y0 += s0sum + b3v; // DT = 1.0; y now = state entering step t
      y1 += s1sum + b3v;
      if (tid == 0) {
        float2 o{y0, y1};
        *(float2*)&yo[t * BATCH] = o; // out[t] = Y_t; ack drains during this step
      }
      {
        const float xaN0 = (i < 7) ? xa0[i + 1] : xn[0].x * w10 + b1j;
        const float xaN1 = (i < 7) ? xa1[i + 1] : xn[0].y * w10 + b1j;
        base0 = __builtin_fmaf(b3v, w11, __builtin_fmaf(y0, w11, xaN0));
        base1 = __builtin_fmaf(b3v, w11, __builtin_fmaf(y1, w11, xaN1));
      }

      // --- s01 + its DPP reduce (hides under tiles-2,3 MFMA block) ---
      const float s01 = tanh_e(acc0[0] + b2c[0]) * w3c[0] +
                        tanh_e(acc1[0] + b2c[1]) * w3c[1];
      const float r01 = row16_sum_to_lane15(s01);

      // --- tiles 2,3 ---
      {
        const bf16x8 a = __builtin_bit_cast(bf16x8, areg[0]);
        acc2 = __builtin_amdgcn_mfma_f32_16x16x32_bf16(a, __builtin_bit_cast(bf16x8, bf[2][0]), kZero, 0, 0, 0);
        acc3 = __builtin_amdgcn_mfma_f32_16x16x32_bf16(a, __builtin_bit_cast(bf16x8, bf[3][0]), kZero, 0, 0, 0);
      }
#pragma unroll
      for (int kc = 1; kc < 8; ++kc) {
        const bf16x8 a = __builtin_bit_cast(bf16x8, areg[kc]);
        acc2 = __builtin_amdgcn_mfma_f32_16x16x32_bf16(a, __builtin_bit_cast(bf16x8, bf[2][kc]), acc2, 0, 0, 0);
        acc3 = __builtin_amdgcn_mfma_f32_16x16x32_bf16(a, __builtin_bit_cast(bf16x8, bf[3][kc]), acc3, 0, 0, 0);
      }

      const float s23 = tanh_e(acc2[0] + b2c[2]) * w3c[2] +
                        tanh_e(acc3[0] + b2c[3]) * w3c[3];
      const float r = row16_sum_to_lane15(s23) + r01;

      if ((lane & 15) == 15 && lane < 32)
        partial[lane >> 4][wave] = r;
      __syncthreads(); // bar2: partials visible (folded at top of next step)
    }

    if (tb + 8 < SEQ) {
#pragma unroll
      for (int i = 0; i < 8; ++i) xb[i] = xn[i];
#pragma unroll
      for (int i = 0; i < 8; ++i) {
        xa0[i] = xb[i].x * w10 + b1j;
        xa1[i] = xb[i].y * w10 + b1j;
      }
    }
  }
}

extern "C" void kernel_launch(void* const* d_in, const int* in_sizes, int n_in,
                              void* d_out, int out_size, void* d_ws, size_t ws_size,
                              hipStream_t stream) {
  const float* x  = (const float*)d_in[0];
  const float* W1 = (const float*)d_in[1];
  const float* b1 = (const float*)d_in[2];
  const float* W2 = (const float*)d_in[3];
  const float* b2 = (const float*)d_in[4];
  const float* W3 = (const float*)d_in[5];
  const float* b3 = (const float*)d_in[6];
  const float* s0 = (const float*)d_in[7];
  unsigned short* ws = (unsigned short*)d_ws; // 65536 bf16 = 128 KB
  float* out = (float*)d_out;

  pack_w2_kernel<<<256, 256, 0, stream>>>(W2, ws);
  odenet_kernel<<<256, 256, 0, stream>>>(x, W1, b1, ws, b2, W3, b3, s0, out);
}

// Round 12
// 1310.083 us; speedup vs baseline: 1.0372x; 1.0372x over previous
//
#include <hip/hip_runtime.h>

// ODENet: y_{t+1} = y_t + f(x_t, y_t),  f = W3^T tanh(W2^T tanh(x*W1[0] + y*W1[1] + b1) + b2) + b3
// out[t][b] = y_t (pre-update state).  SEQ=2048 sequential steps, BATCH=512 independent chains.
//
// Round-12: 256 WGs x 512 threads (8 waves = 2 waves/SIMD). MFMA BLOCKS ITS WAVE on CDNA4,
// so with 1 wave/SIMD (R7-R11) VALU serialized after MFMA; with 2 waves/SIMD the partner
// wave's VALU fills each MFMA-blocked window (R6 measured 98% combined util cross-wave).
// Each wave owns 2 column-tiles (16 MFMAs/step) -> same 620 cyc/SIMD MFMA pipe floor.
//  - Linearized h1 hand-off: T = tanh(base(t+1)), E = w11*(1-T^2) computed in the MFMA
//    window; post-fold path = fma(s,E,T) -> pack -> write (~30 cyc, was ~100).
//    err <= (w11 f)^2/2 ~ 3e-5 per step, 100x below bf16 h1 rounding.
//  - fold reads partial[2][8] (broadcast b128 x4); partials pre-init -b3/8 so step-0 f=0.
//  - burst y-store per 8-step block (tid0), exp2-tanh, LDA=288 padded A_lds, M=2 rows 0,4.

#define SEQ 2048
#define BATCH 512
#define HID 256
#define LDA 288  // padded row stride (ushorts); rows land on disjoint bank halves

typedef __bf16 bf16x8 __attribute__((ext_vector_type(8)));
typedef short short8 __attribute__((ext_vector_type(8)));
typedef float f32x4 __attribute__((ext_vector_type(4)));

__device__ __forceinline__ unsigned short f2bf_rne(float f) {
  unsigned u = __builtin_bit_cast(unsigned, f);
  u += 0x7fffu + ((u >> 16) & 1u);
  return (unsigned short)(u >> 16);
}

// Exact tanh via exp2: tanh(x) = 1 - 2/(exp2(2*log2e*x) + 1). No clamp needed.
__device__ __forceinline__ float tanh_e(float x) {
  float t = __builtin_amdgcn_exp2f(x * 2.8853900817779268f);
  return __builtin_fmaf(-2.f, __builtin_amdgcn_rcpf(t + 1.f), 1.f);
}

// Sum over each 16-lane DPP row; valid in lane 15 of the row.
__device__ __forceinline__ float row16_sum_to_lane15(float v) {
  int s;
  s = __builtin_amdgcn_update_dpp(0, __builtin_bit_cast(int, v), 0x111, 0xf, 0xf, true);
  v += __builtin_bit_cast(float, s);
  s = __builtin_amdgcn_update_dpp(0, __builtin_bit_cast(int, v), 0x112, 0xf, 0xf, true);
  v += __builtin_bit_cast(float, s);
  s = __builtin_amdgcn_update_dpp(0, __builtin_bit_cast(int, v), 0x114, 0xf, 0xf, true);
  v += __builtin_bit_cast(float, s);
  s = __builtin_amdgcn_update_dpp(0, __builtin_bit_cast(int, v), 0x118, 0xf, 0xf, true);
  v += __builtin_bit_cast(float, s);
  return v;
}

// Pack W2 (256x256 fp32, row-major [k][c]) into bf16 B-fragments.
// ws[(((tile*8)+kc)*64 + lane)*8 + e] = bf16(W2[k][c]) with
//   k = kc*32 + (lane>>4)*8 + e,  c = tile*16 + (lane&15)
__global__ void pack_w2_kernel(const float* __restrict__ W2,
                               unsigned short* __restrict__ ws) {
  int idx = blockIdx.x * 256 + threadIdx.x;     // 0..65535
  int e    = idx & 7;
  int l    = (idx >> 3) & 63;
  int kc   = (idx >> 9) & 7;
  int tile = idx >> 12;                         // 0..15
  int k = kc * 32 + (l >> 4) * 8 + e;
  int c = tile * 16 + (l & 15);
  ws[idx] = f2bf_rne(W2[k * HID + c]);
}

__global__ __launch_bounds__(512, 2) void odenet_kernel(
    const float* __restrict__ x, const float* __restrict__ W1,
    const float* __restrict__ b1, const unsigned short* __restrict__ wsW2,
    const float* __restrict__ b2, const float* __restrict__ W3,
    const float* __restrict__ b3, const float* __restrict__ state0,
    float* __restrict__ out) {
  __shared__ __align__(16) unsigned short A_lds[2 * LDA]; // h1 bf16, padded rows
  __shared__ __align__(16) float partial[2][8];           // [chain][wave]

  const int tid  = threadIdx.x;   // 0..511
  const int lane = tid & 63;
  const int wave = tid >> 6;      // 0..7
  const int rh   = tid >> 8;      // own h1 row (chain) for production
  const int j    = tid & 255;     // own h1 column
  const int b0   = blockIdx.x * 2;

  // --- persistent constants ---
  const float w10 = W1[j];
  const float w11 = W1[HID + j];
  const float b1j = b1[j];
  const float b3v = b3[0];
  // wave owns tiles {2w, 2w+1}: columns c0 (tile 2w), c1 (tile 2w+1)
  const int c0 = wave * 32 + (lane & 15);
  const int c1 = c0 + 16;
  const float b2c0 = b2[c0], w3c0 = W3[c0];
  const float b2c1 = b2[c1], w3c1 = W3[c1];

  // --- B fragments: 2 tiles x 8 kc = 64 VGPRs ---
  short8 bf0[8], bf1[8];
  {
    const short8* wp = (const short8*)wsW2;
    const int t0 = wave * 2;
#pragma unroll
    for (int kc = 0; kc < 8; ++kc) {
      bf0[kc] = wp[((t0    ) * 8 + kc) * 64 + lane];
      bf1[kc] = wp[((t0 + 1) * 8 + kc) * 64 + lane];
    }
  }

  // --- A-read address, unmasked (R10-verified): lanes with (lane>>2)&1==0 read row0,
  //     ==1 read row1; 8-way same-address dup within 16-lane groups = broadcast (free).
  const int aoff = ((lane >> 2) & 1) * LDA + (lane >> 4) * 8; // ushort index

  const f32x4 kZero = {0.f, 0.f, 0.f, 0.f};

  float y0 = state0[b0];
  float y1 = state0[b0 + 1];

  const float* xp = x + b0 + rh;  // own chain's x stream
  float* yo = out + b0;

  // x prefetch double buffer (8 steps ahead); xa = x*w10 + b1 (own chain)
  float xb[8], xn[8], xa[8];
#pragma unroll
  for (int i = 0; i < 8; ++i) xb[i] = xp[i * BATCH];
#pragma unroll
  for (int i = 0; i < 8; ++i) xa[i] = xb[i] * w10 + b1j;

  // --- T/E for step 0 (linearization point): base'' = xa(0) + w11*y_own + w11*b3 ---
  float y_own = rh ? y1 : y0;
  float T = tanh_e(__builtin_fmaf(b3v, w11, __builtin_fmaf(y_own, w11, xa[0])));
  float E = w11 * __builtin_fmaf(-T, T, 1.f);

  // --- partials init: 16 entries of -b3/8 -> step-0 fold sums to -b3, f = 0 exactly ---
  if (tid < 16) ((float*)partial)[tid] = -0.125f * b3v;
  __syncthreads(); // partials visible (acts as the "bar2" preceding step 0)

  for (int tb = 0; tb < SEQ; tb += 8) {
    float xanb = 0.f; // xa of next block's step 0
    if (tb + 8 < SEQ) {
      const float* xq = xp + (tb + 8) * BATCH;
#pragma unroll
      for (int i = 0; i < 8; ++i) xn[i] = xq[i * BATCH];
      xanb = xn[0] * w10 + b1j;
    }

    float2 yh[8]; // yh[i] = Y_{tb+i} (state entering step tb+i)

#pragma unroll
    for (int i = 0; i < 8; ++i) {
      // --- fold partials of step t-1: broadcast reads + 7 adds (per chain) ---
      const f32x4 q0a = *(const f32x4*)&partial[0][0];
      const f32x4 q0b = *(const f32x4*)&partial[0][4];
      const f32x4 q1a = *(const f32x4*)&partial[1][0];
      const f32x4 q1b = *(const f32x4*)&partial[1][4];
      const float s0sum = ((q0a[0] + q0a[1]) + (q0a[2] + q0a[3])) +
                          ((q0b[0] + q0b[1]) + (q0b[2] + q0b[3])); // = f0 - b3
      const float s1sum = ((q1a[0] + q1a[1]) + (q1a[2] + q1a[3])) +
                          ((q1b[0] + q1b[1]) + (q1b[2] + q1b[3]));

      // --- h1 (own value only), linearized around precomputed T/E ---
      const float s_own = rh ? s1sum : s0sum;
      A_lds[rh * LDA + j] = f2bf_rne(__builtin_fmaf(s_own, E, T));
      __syncthreads(); // bar1: h1 visible

      // --- A-fragments (unconditional; dup reads broadcast; padded rows) ---
      short8 areg[8];
#pragma unroll
      for (int kc = 0; kc < 8; ++kc)
        areg[kc] = *(const short8*)&A_lds[aoff + kc * 32];

      // --- 2 tiles x K=256 (16 MFMAs; partner wave's VALU fills blocked windows) ---
      f32x4 acc0, acc1;
      {
        const bf16x8 a = __builtin_bit_cast(bf16x8, areg[0]);
        acc0 = __builtin_amdgcn_mfma_f32_16x16x32_bf16(a, __builtin_bit_cast(bf16x8, bf0[0]), kZero, 0, 0, 0);
        acc1 = __builtin_amdgcn_mfma_f32_16x16x32_bf16(a, __builtin_bit_cast(bf16x8, bf1[0]), kZero, 0, 0, 0);
      }
#pragma unroll
      for (int kc = 1; kc < 8; ++kc) {
        const bf16x8 a = __builtin_bit_cast(bf16x8, areg[kc]);
        acc0 = __builtin_amdgcn_mfma_f32_16x16x32_bf16(a, __builtin_bit_cast(bf16x8, bf0[kc]), acc0, 0, 0, 0);
        acc1 = __builtin_amdgcn_mfma_f32_16x16x32_bf16(a, __builtin_bit_cast(bf16x8, bf1[kc]), acc1, 0, 0, 0);
      }

      // --- VALU in the partner-hidden window: y update, history, next T/E ---
      y0 += s0sum + b3v; // DT = 1.0; y now = Y_t
      y1 += s1sum + b3v;
      yh[i] = float2{y0, y1};
      y_own = rh ? y1 : y0;
      {
        const float xaN = (i < 7) ? xa[i + 1] : xanb;
        T = tanh_e(__builtin_fmaf(b3v, w11, __builtin_fmaf(y_own, w11, xaN)));
        E = w11 * __builtin_fmaf(-T, T, 1.f);
      }

      // --- tail: h2 = tanh(acc+b2), dot W3, 16-lane DPP reduce ---
      const float s = tanh_e(acc0[0] + b2c0) * w3c0 +
                      tanh_e(acc1[0] + b2c1) * w3c1;
      const float r = row16_sum_to_lane15(s);
      if ((lane & 15) == 15 && lane < 32)
        partial[lane >> 4][wave] = r; // chain = lane>>4
      __syncthreads(); // bar2: partials visible (folded at top of next step)
    }

    // --- burst-store outputs (one vmcnt drain per 8 steps, tid 0 only) ---
    if (tid == 0) {
#pragma unroll
      for (int i = 0; i < 8; ++i)
        *(float2*)&yo[(tb + i) * BATCH] = yh[i]; // out[t] = Y_t
    }

    if (tb + 8 < SEQ) {
#pragma unroll
      for (int i = 0; i < 8; ++i) xb[i] = xn[i];
#pragma unroll
      for (int i = 0; i < 8; ++i) xa[i] = xb[i] * w10 + b1j;
    }
  }
}

extern "C" void kernel_launch(void* const* d_in, const int* in_sizes, int n_in,
                              void* d_out, int out_size, void* d_ws, size_t ws_size,
                              hipStream_t stream) {
  const float* x  = (const float*)d_in[0];
  const float* W1 = (const float*)d_in[1];
  const float* b1 = (const float*)d_in[2];
  const float* W2 = (const float*)d_in[3];
  const float* b2 = (const float*)d_in[4];
  const float* W3 = (const float*)d_in[5];
  const float* b3 = (const float*)d_in[6];
  const float* s0 = (const float*)d_in[7];
  unsigned short* ws = (unsigned short*)d_ws; // 65536 bf16 = 128 KB
  float* out = (float*)d_out;

  pack_w2_kernel<<<256, 256, 0, stream>>>(W2, ws);
  odenet_kernel<<<256, 512, 0, stream>>>(x, W1, b1, ws, b2, W3, b3, s0, out);
}

// Round 13
// 1189.609 us; speedup vs baseline: 1.1422x; 1.1013x over previous
//
#include <hip/hip_runtime.h>

// ODENet: y_{t+1} = y_t + f(x_t, y_t),  f = W3^T tanh(W2^T tanh(x*W1[0] + y*W1[1] + b1) + b2) + b3
// out[t][b] = y_t (pre-update state).  SEQ=2048 sequential steps, BATCH=512 independent chains.
//
// Round-13: drain-free main loop on the R12 skeleton (256 WGs x 512 thr, 8 waves, M=2 rows 0/4):
//  - x preloaded to LDS (16 KB) at kernel start: ZERO global loads in the loop. The old
//    per-8-block x prefetch was vmcnt(0)-drained at the next barrier (~90 cyc/step leak).
//  - y staged to LDS (16 KB) per step; one global flush after the loop: ZERO global stores
//    in the loop. Loop is now flat (no 8-step blocking).
//  - per-chain fold: each thread reads only its own chain's partials (2x b128 broadcast).
//  - retained (all bench-verified): linearized h1 hand-off (T/E in MFMA shadow), exp2-tanh,
//    LDA=288 padded A_lds, unmasked dup A-reads (free 8-way broadcast), split DPP reduce,
//    partial init -b3/8 so step-0 f=0.

#define SEQ 2048
#define BATCH 512
#define HID 256
#define LDA 288  // padded row stride (ushorts); rows land on disjoint bank halves

typedef __bf16 bf16x8 __attribute__((ext_vector_type(8)));
typedef short short8 __attribute__((ext_vector_type(8)));
typedef float f32x4 __attribute__((ext_vector_type(4)));

__device__ __forceinline__ unsigned short f2bf_rne(float f) {
  unsigned u = __builtin_bit_cast(unsigned, f);
  u += 0x7fffu + ((u >> 16) & 1u);
  return (unsigned short)(u >> 16);
}

// Exact tanh via exp2: tanh(x) = 1 - 2/(exp2(2*log2e*x) + 1). No clamp needed.
__device__ __forceinline__ float tanh_e(float x) {
  float t = __builtin_amdgcn_exp2f(x * 2.8853900817779268f);
  return __builtin_fmaf(-2.f, __builtin_amdgcn_rcpf(t + 1.f), 1.f);
}

// Sum over each 16-lane DPP row; valid in lane 15 of the row.
__device__ __forceinline__ float row16_sum_to_lane15(float v) {
  int s;
  s = __builtin_amdgcn_update_dpp(0, __builtin_bit_cast(int, v), 0x111, 0xf, 0xf, true);
  v += __builtin_bit_cast(float, s);
  s = __builtin_amdgcn_update_dpp(0, __builtin_bit_cast(int, v), 0x112, 0xf, 0xf, true);
  v += __builtin_bit_cast(float, s);
  s = __builtin_amdgcn_update_dpp(0, __builtin_bit_cast(int, v), 0x114, 0xf, 0xf, true);
  v += __builtin_bit_cast(float, s);
  s = __builtin_amdgcn_update_dpp(0, __builtin_bit_cast(int, v), 0x118, 0xf, 0xf, true);
  v += __builtin_bit_cast(float, s);
  return v;
}

// Pack W2 (256x256 fp32, row-major [k][c]) into bf16 B-fragments.
// ws[(((tile*8)+kc)*64 + lane)*8 + e] = bf16(W2[k][c]) with
//   k = kc*32 + (lane>>4)*8 + e,  c = tile*16 + (lane&15)
__global__ void pack_w2_kernel(const float* __restrict__ W2,
                               unsigned short* __restrict__ ws) {
  int idx = blockIdx.x * 256 + threadIdx.x;     // 0..65535
  int e    = idx & 7;
  int l    = (idx >> 3) & 63;
  int kc   = (idx >> 9) & 7;
  int tile = idx >> 12;                         // 0..15
  int k = kc * 32 + (l >> 4) * 8 + e;
  int c = tile * 16 + (l & 15);
  ws[idx] = f2bf_rne(W2[k * HID + c]);
}

__global__ __launch_bounds__(512, 2) void odenet_kernel(
    const float* __restrict__ x, const float* __restrict__ W1,
    const float* __restrict__ b1, const unsigned short* __restrict__ wsW2,
    const float* __restrict__ b2, const float* __restrict__ W3,
    const float* __restrict__ b3, const float* __restrict__ state0,
    float* __restrict__ out) {
  __shared__ __align__(16) unsigned short A_lds[2 * LDA]; // h1 bf16, padded rows
  __shared__ __align__(16) float partial[2][8];           // [chain][wave]
  __shared__ __align__(16) float2 x_lds[SEQ];             // 16 KB: this WG's x pairs
  __shared__ __align__(16) float2 y_lds[SEQ];             // 16 KB: output staging

  const int tid  = threadIdx.x;   // 0..511
  const int lane = tid & 63;
  const int wave = tid >> 6;      // 0..7
  const int rh   = tid >> 8;      // own chain (h1 row)
  const int j    = tid & 255;     // own h1 column
  const int b0   = blockIdx.x * 2;

  // --- persistent constants ---
  const float w10 = W1[j];
  const float w11 = W1[HID + j];
  const float b1j = b1[j];
  const float b3v = b3[0];
  // wave owns tiles {2w, 2w+1}: columns c0 (tile 2w), c1 (tile 2w+1)
  const int c0 = wave * 32 + (lane & 15);
  const int c1 = c0 + 16;
  const float b2c0 = b2[c0], w3c0 = W3[c0];
  const float b2c1 = b2[c1], w3c1 = W3[c1];

  // --- B fragments: 2 tiles x 8 kc = 64 VGPRs ---
  short8 bf0[8], bf1[8];
  {
    const short8* wp = (const short8*)wsW2;
    const int t0 = wave * 2;
#pragma unroll
    for (int kc = 0; kc < 8; ++kc) {
      bf0[kc] = wp[((t0    ) * 8 + kc) * 64 + lane];
      bf1[kc] = wp[((t0 + 1) * 8 + kc) * 64 + lane];
    }
  }

  // --- preload x into LDS (one-time; removes ALL global loads from the loop) ---
  {
    const float* xg = x + b0;
#pragma unroll
    for (int k = 0; k < 4; ++k) {
      const int t = tid + k * 512;
      x_lds[t] = *(const float2*)&xg[t * BATCH];
    }
  }

  // --- A-read address, unmasked: 8-way same-address dup = free broadcast ---
  const int aoff = ((lane >> 2) & 1) * LDA + (lane >> 4) * 8; // ushort index

  const f32x4 kZero = {0.f, 0.f, 0.f, 0.f};

  const float2 y_init = *(const float2*)&state0[b0];
  float y_own = rh ? y_init.y : y_init.x;

  // --- partials init: fold of own chain sums 8 entries of -b3/8 -> s_own = -b3, f = 0 ---
  if (tid < 16) ((float*)partial)[tid] = -0.125f * b3v;
  __syncthreads(); // x_lds + partials visible (acts as bar2 preceding step 0)

  // --- T/E for step 0: base'' = xa(0) + w11*y + w11*b3 ---
  {
    const float2 x0 = x_lds[0];
    const float xv = rh ? x0.y : x0.x;
    const float xa0 = __builtin_fmaf(xv, w10, b1j);
    const float T0 = tanh_e(__builtin_fmaf(b3v, w11, __builtin_fmaf(y_own, w11, xa0)));
    // (names reused below)
  }
  float2 xr0 = x_lds[0];
  float T, E;
  {
    const float xv = rh ? xr0.y : xr0.x;
    const float xa0 = __builtin_fmaf(xv, w10, b1j);
    T = tanh_e(__builtin_fmaf(b3v, w11, __builtin_fmaf(y_own, w11, xa0)));
    E = w11 * __builtin_fmaf(-T, T, 1.f);
  }

  for (int t = 0; t < SEQ; ++t) {
    // --- head: fold OWN chain's partials (step t-1), linearized h1, write ---
    const f32x4 qa = *(const f32x4*)&partial[rh][0];
    const f32x4 qb = *(const f32x4*)&partial[rh][4];
    const float s_own = ((qa[0] + qa[1]) + (qa[2] + qa[3])) +
                        ((qb[0] + qb[1]) + (qb[2] + qb[3])); // = f(t-1) - b3
    A_lds[rh * LDA + j] = f2bf_rne(__builtin_fmaf(s_own, E, T));
    __syncthreads(); // bar1: h1 visible

    // --- x for step t+1 (broadcast LDS read, latency hidden under MFMAs) ---
    const float2 xr = x_lds[(t + 1 < SEQ) ? t + 1 : t];

    // --- A-fragments (unconditional; dup reads broadcast; padded rows) ---
    short8 areg[8];
#pragma unroll
    for (int kc = 0; kc < 8; ++kc)
      areg[kc] = *(const short8*)&A_lds[aoff + kc * 32];

    // --- 2 tiles x K=256 (16 MFMAs) ---
    f32x4 acc0, acc1;
    {
      const bf16x8 a = __builtin_bit_cast(bf16x8, areg[0]);
      acc0 = __builtin_amdgcn_mfma_f32_16x16x32_bf16(a, __builtin_bit_cast(bf16x8, bf0[0]), kZero, 0, 0, 0);
      acc1 = __builtin_amdgcn_mfma_f32_16x16x32_bf16(a, __builtin_bit_cast(bf16x8, bf1[0]), kZero, 0, 0, 0);
    }
#pragma unroll
    for (int kc = 1; kc < 8; ++kc) {
      const bf16x8 a = __builtin_bit_cast(bf16x8, areg[kc]);
      acc0 = __builtin_amdgcn_mfma_f32_16x16x32_bf16(a, __builtin_bit_cast(bf16x8, bf0[kc]), acc0, 0, 0, 0);
      acc1 = __builtin_amdgcn_mfma_f32_16x16x32_bf16(a, __builtin_bit_cast(bf16x8, bf1[kc]), acc1, 0, 0, 0);
    }

    // --- shadow VALU (independent of acc): y update -> Y_t, stage to LDS, next T/E ---
    y_own += s_own + b3v; // DT = 1.0; y_own = state entering step t
    if (j == 0) ((float*)&y_lds[t])[rh] = y_own; // tid 0 -> .x, tid 256 -> .y
    {
      const float xv = rh ? xr.y : xr.x;
      const float xaN = __builtin_fmaf(xv, w10, b1j);
      T = tanh_e(__builtin_fmaf(b3v, w11, __builtin_fmaf(y_own, w11, xaN)));
      E = w11 * __builtin_fmaf(-T, T, 1.f);
    }

    // --- tail: h2 = tanh(acc+b2), dot W3, 16-lane DPP reduce ---
    const float s = tanh_e(acc0[0] + b2c0) * w3c0 +
                    tanh_e(acc1[0] + b2c1) * w3c1;
    const float r = row16_sum_to_lane15(s);
    if ((lane & 15) == 15 && lane < 32)
      partial[lane >> 4][wave] = r; // chain = lane>>4
    __syncthreads(); // bar2: partials visible (folded at top of next step)
  }

  // --- flush y staging to global (one-time; L2 merges the 8B/row slices) ---
#pragma unroll
  for (int k = 0; k < 4; ++k) {
    const int t = tid + k * 512;
    *(float2*)&out[t * BATCH + b0] = y_lds[t];
  }
}

extern "C" void kernel_launch(void* const* d_in, const int* in_sizes, int n_in,
                              void* d_out, int out_size, void* d_ws, size_t ws_size,
                              hipStream_t stream) {
  const float* x  = (const float*)d_in[0];
  const float* W1 = (const float*)d_in[1];
  const float* b1 = (const float*)d_in[2];
  const float* W2 = (const float*)d_in[3];
  const float* b2 = (const float*)d_in[4];
  const float* W3 = (const float*)d_in[5];
  const float* b3 = (const float*)d_in[6];
  const float* s0 = (const float*)d_in[7];
  unsigned short* ws = (unsigned short*)d_ws; // 65536 bf16 = 128 KB
  float* out = (float*)d_out;

  pack_w2_kernel<<<256, 256, 0, stream>>>(W2, ws);
  odenet_kernel<<<256, 512, 0, stream>>>(x, W1, b1, ws, b2, W3, b3, s0, out);
}